// Round 19
// baseline (359.889 us; speedup 1.0000x reference)
//
#include <hip/hip_runtime.h>
#include <hip/hip_fp16.h>
#include <math.h>

// Problem constants (from reference file)
constexpr int N_NODES  = 50000;
constexpr int N_EDGES  = 1600000;
constexpr int G_GRAPHS = 64;
constexpr int D        = 32;
constexpr int D_ATTR   = 16;
constexpr int N_RBF    = 8;

// rw(len) lookup table: 8192 intervals over [0, LMAX], nearest-neighbor, fp16.
constexpr int   TBL      = 8192;
constexpr int   TBL_ROWS = TBL + 1;
constexpr float LMAX     = 10.0f;

// Final per-node bucket layout (SoA for coalesced conv reads). deg ~ Poisson(32).
constexpr int BUCKET = 80;

// dst-tiles of 64 nodes; per-tile contiguous streams filled by counting sort.
constexpr int NT     = 64;
constexpr int NTILES = (N_NODES + NT - 1) / NT;  // 782
constexpr int TCAP   = 2432;                     // Poisson(2048) +8.5 sigma
// Pipeline (r31): memset(tile_cursor) -> MEGA(scatter+init+table, one
// dispatch: the three are mutually independent and all latency-bound at
// 21-28% occupancy — overlap them on the machine instead of serializing
// 57+57us) -> LDS-staged shuffle -> conv x3 -> readout.
// DO-NOT-REPEAT ledger:
//  r16: PER-EDGE returning atomics, 782 counters (~2046/addr) -> 380us.
//    (Per-BLOCK cursor atomics, 391/addr chains, are fine — R4/R18.)
//  R12: direct scattered SoA writes (4 planes/record) -> 240MB WRITE, 130us.
//  R13: 16B AoS bucket for conv -> conv streams 16B/rec x3 layers, +30us.
//  R15 WIN: LDS-staged shuffle (coalesced 4-plane writeout) -13.4us.
//  R16 WIN: merged prep -5.3us. R17: (512,8) on prep regressed (VGPR squeeze).
//  R18 WIN: scan deleted, hist folded into scatter (R4 form) -8us.
//  r22/R9: conv accumulation via LDS atomicAdd -> 356us/conv (7x).
//  r23/R10: conv software-pipelining folded by compiler — neutral.
//  R11: conv (256,8) adopted (44.0 vs 45.2).
constexpr int EPB      = 4096;                         // R4/R18 scatter config
constexpr int MTHREADS = 1024;
constexpr int EPV      = EPB / MTHREADS;               // 4 edges/thread
constexpr int NBLK1    = (N_EDGES + EPB - 1) / EPB;    // 391

constexpr int NSLOT = NTILES * NT * BUCKET;  // bucket slots total
constexpr int TSLOT = NT * BUCKET;           // 5120 slots per tile

// mega kernel block ranges (1024 threads/block)
constexpr int SCAT_BLKS  = NBLK1;                                // 391
constexpr int INIT_BLKS  = (N_NODES * 32 + MTHREADS - 1) / MTHREADS;  // 1563
constexpr int TABLE_BLKS = (3 * TBL_ROWS + MTHREADS - 1) / MTHREADS;  // 25
constexpr int MEGA_BLKS  = SCAT_BLKS + INIT_BLKS + TABLE_BLKS;   // 1979

typedef unsigned int  uint4v  __attribute__((ext_vector_type(4)));
typedef unsigned int  uint2v  __attribute__((ext_vector_type(2)));

__device__ __forceinline__ float silu(float x) {
    return x / (1.0f + __expf(-x));
}
__device__ __forceinline__ float h2f_bits(unsigned short u) {
    return __half2float(__ushort_as_half(u));
}
__device__ __forceinline__ __half2 h2u(unsigned v) {
    union { unsigned u; __half2 h; } c; c.u = v; return c.h;
}

// acc[j] += (tab*hm)[channel cg*8+j] * sw for one record's 8-channel quad.
__device__ __forceinline__ void accum8(uint4v t, uint4v m, float sw, float (&acc)[8]) {
    float2 p0 = __half22float2(__hmul2(h2u(t.x), h2u(m.x)));
    float2 p1 = __half22float2(__hmul2(h2u(t.y), h2u(m.y)));
    float2 p2 = __half22float2(__hmul2(h2u(t.z), h2u(m.z)));
    float2 p3 = __half22float2(__hmul2(h2u(t.w), h2u(m.w)));
    acc[0] = fmaf(p0.x, sw, acc[0]); acc[1] = fmaf(p0.y, sw, acc[1]);
    acc[2] = fmaf(p1.x, sw, acc[2]); acc[3] = fmaf(p1.y, sw, acc[3]);
    acc[4] = fmaf(p2.x, sw, acc[4]); acc[5] = fmaf(p2.y, sw, acc[5]);
    acc[6] = fmaf(p3.x, sw, acc[6]); acc[7] = fmaf(p3.y, sw, acc[7]);
}

// ---------------------------------------------------------------------------
// 1) MEGA: blocks [0,SCAT_BLKS) run the R18 scatter (per-block LDS hist ->
//    one tile_cursor atomic per nonzero tile -> LDS-ranked scatter);
//    [SCAT,SCAT+INIT) run node-init; rest build the rw tables. All three
//    are mutually independent; tile_cursor pre-zeroed by hipMemsetAsync.
//    Scatter blocks first -> issued first; init blocks backfill idle SIMDs.
// ---------------------------------------------------------------------------
__global__ __launch_bounds__(MTHREADS, 4) void mega_kernel(
        const int* __restrict__ eidx,
        const float* __restrict__ pos,
        const float* __restrict__ period,
        const float* __restrict__ wsh,
        int* __restrict__ tile_cursor,
        uint4v* __restrict__ bins,
        const int* __restrict__ x,
        const float* __restrict__ W_elem,
        const float* __restrict__ W0,
        const float* __restrict__ b0,
        const float* __restrict__ Wmsg0,
        const float* __restrict__ Wself0,
        const float* __restrict__ Wattr,
        const float* __restrict__ bconv,
        __half* __restrict__ hm0,
        float* __restrict__ hs0,
        float* __restrict__ xa1,
        float* __restrict__ xa2,
        float* __restrict__ out,
        const float* __restrict__ Wr1,
        const float* __restrict__ br1,
        const float* __restrict__ Wr2,
        __half* __restrict__ table) {
    __shared__ int hist[NTILES];
    __shared__ int basev[NTILES];
    int tid = threadIdx.x;
    int blk = blockIdx.x;

    if (blk < SCAT_BLKS) {
        // ---- scatter branch (R18 body) ----
        int e0 = blk * EPB;
        for (int i = tid; i < NTILES; i += MTHREADS) hist[i] = 0;
        __syncthreads();
#pragma unroll
        for (int i = 0; i < EPV; ++i) {
            int e = e0 + tid + MTHREADS * i;
            if (e < N_EDGES) atomicAdd(&hist[eidx[N_EDGES + e] >> 6], 1);
        }
        __syncthreads();
        for (int t = tid; t < NTILES; t += MTHREADS) {
            int cnt = hist[t];
            basev[t] = (cnt > 0) ? atomicAdd(&tile_cursor[t], cnt) : 0;
            hist[t] = 0;
        }
        __syncthreads();

        int   sarr[EPV], darr[EPV];
        float vx[EPV], vy[EPV], vz[EPV];
#pragma unroll
        for (int i = 0; i < EPV; ++i) {
            int e  = e0 + tid + MTHREADS * i;
            int ec = (e < N_EDGES) ? e : (N_EDGES - 1);
            int s = eidx[ec];
            int d = eidx[N_EDGES + ec];
            sarr[i] = s;
            darr[i] = d;
            vx[i] = pos[d * 3 + 0] - pos[s * 3 + 0] + period[ec * 3 + 0];
            vy[i] = pos[d * 3 + 1] - pos[s * 3 + 1] + period[ec * 3 + 1];
            vz[i] = pos[d * 3 + 2] - pos[s * 3 + 2] + period[ec * 3 + 2];
        }
        asm volatile("" ::
            "v"(vx[0]), "v"(vx[1]), "v"(vx[2]), "v"(vx[3]),
            "v"(vy[0]), "v"(vy[1]), "v"(vy[2]), "v"(vy[3]),
            "v"(vz[0]), "v"(vz[1]), "v"(vz[2]), "v"(vz[3]),
            "v"(sarr[0]), "v"(sarr[1]), "v"(sarr[2]), "v"(sarr[3]),
            "v"(darr[0]), "v"(darr[1]), "v"(darr[2]), "v"(darr[3]));
#pragma unroll
        for (int i = 0; i < EPV; ++i) {
            int e = e0 + tid + MTHREADS * i;
            if (e >= N_EDGES) continue;
            float len = sqrtf(vx[i] * vx[i] + vy[i] * vy[i] + vz[i] * vz[i]);
            float inv = 1.0f / (len + 1e-9f);
            int idx = (int)fminf(len * ((float)TBL / LMAX) + 0.5f, (float)TBL);
            float sw[3];
#pragma unroll
            for (int l = 0; l < 3; ++l)
                sw[l] = wsh[l * 4 + 0] +
                        (vx[i] * wsh[l * 4 + 1] + vy[i] * wsh[l * 4 + 2] + vz[i] * wsh[l * 4 + 3]) * inv;
            int tile = darr[i] >> 6;
            int rank = atomicAdd(&hist[tile], 1);
            int slot = basev[tile] + rank;
            if (slot < TCAP) {
                unsigned u0 = (unsigned)__half_as_ushort(__float2half(sw[0]));
                unsigned u1 = (unsigned)__half_as_ushort(__float2half(sw[1]));
                unsigned u2 = (unsigned)__half_as_ushort(__float2half(sw[2]));
                uint4v r;
                r.x = (unsigned)sarr[i] | ((unsigned)idx << 16);
                r.y = (unsigned)(darr[i] & (NT - 1));
                r.z = u0 | (u1 << 16);
                r.w = u2;
                bins[(size_t)tile * TCAP + slot] = r;
            }
        }
        return;
    }
    if (blk < SCAT_BLKS + INIT_BLKS) {
        // ---- node-init branch ----
        int t = (blk - SCAT_BLKS) * MTHREADS + tid;
        if (t < G_GRAPHS) out[t] = 0.0f;
        int n = t >> 5, c = t & 31;
        if (n >= N_NODES) return;
        int sp = x[n];
        const float* we = W_elem + sp * D_ATTR;
        float xv = (c < D_ATTR) ? we[c] : 0.0f;
        float acc = b0[c];
#pragma unroll
        for (int a = 0; a < D_ATTR; ++a) acc += we[a] * W0[a * D + c];
        float m = 0.0f, s = 0.0f;
#pragma unroll
        for (int j = 0; j < D; ++j) {
            float hj = __shfl(acc, j, 32);
            m = fmaf(hj, Wmsg0[j * D + c], m);
            s = fmaf(hj, Wself0[j * D + c], s);
        }
        float a0 = bconv[0 * D + c], a1 = bconv[1 * D + c], a2 = bconv[2 * D + c];
#pragma unroll
        for (int j = 0; j < D_ATTR; ++j) {
            float xj = __shfl(xv, j, 32);
            a0 = fmaf(xj, Wattr[0 * D_ATTR * D + j * D + c], a0);
            a1 = fmaf(xj, Wattr[1 * D_ATTR * D + j * D + c], a1);
            a2 = fmaf(xj, Wattr[2 * D_ATTR * D + j * D + c], a2);
        }
        hm0[n * D + c] = __float2half(m);
        hs0[n * D + c] = s + a0;
        xa1[n * D + c] = a1;
        xa2[n * D + c] = a2;
        return;
    }
    // ---- table branch ----
    {
        int t = (blk - SCAT_BLKS - INIT_BLKS) * MTHREADS + tid;
        if (t >= 3 * TBL_ROWS) return;
        int l = t / TBL_ROWS;
        int idx = t % TBL_ROWS;
        float len = (float)idx * (LMAX / (float)TBL);
        const float gamma = (8.0f / 5.0f) * (8.0f / 5.0f);  // (N_RBF/CUTOFF)^2
        float rbf[N_RBF];
#pragma unroll
        for (int k = 0; k < N_RBF; ++k) {
            float dd = len - (float)k * (5.0f / 7.0f);  // linspace(0, CUTOFF, 8)
            rbf[k] = __expf(-gamma * dd * dd);
        }
        float outv[D];
#pragma unroll
        for (int c = 0; c < D; ++c) outv[c] = 0.0f;
        for (int j = 0; j < D; ++j) {
            float z = br1[l * D + j];
#pragma unroll
            for (int k = 0; k < N_RBF; ++k) z += rbf[k] * Wr1[l * N_RBF * D + k * D + j];
            z = fmaxf(z, 0.0f);
            const float* w2 = Wr2 + l * D * D + j * D;
#pragma unroll
            for (int c = 0; c < D; ++c) outv[c] += z * w2[c];
        }
        __half* dst = table + ((size_t)(l * TBL_ROWS + idx)) * D;
#pragma unroll
        for (int c = 0; c < D; ++c) dst[c] = __float2half(outv[c]);
    }
}

// ---------------------------------------------------------------------------
// 2b) Shuffle (R15 WIN form): block-per-tile, LDS-staged re-rank then
//     COALESCED writeout of all 4 planes. Zero scattered global writes.
//     tile_total = tile_cursor after scatter (clamped by TCAP).
// ---------------------------------------------------------------------------
__global__ __launch_bounds__(512) void shuffle_kernel(const uint4v* __restrict__ bins,
                                                      const int* __restrict__ tile_total,
                                                      unsigned int* __restrict__ xs,
                                                      unsigned short* __restrict__ swp,
                                                      int* __restrict__ count) {
    __shared__ int lcur[NT];
    __shared__ unsigned sxs[TSLOT];                 // 20 KB
    __shared__ unsigned short ssw[3][TSLOT];        // 30 KB
    int tile = blockIdx.x;
    int tid = threadIdx.x;
    if (tid < NT) lcur[tid] = 0;
    __syncthreads();
    int cnt = tile_total[tile];
    if (cnt > TCAP) cnt = TCAP;
    const uint4v* base = bins + (size_t)tile * TCAP;
    for (int i = tid; i < cnt; i += 512) {
        uint4v r = __builtin_nontemporal_load(base + i);
        int dl = (int)(r.y & 63u);
        int slot = atomicAdd(&lcur[dl], 1);
        if (slot < BUCKET) {
            int g = dl * BUCKET + slot;
            sxs[g] = r.x;
            ssw[0][g] = (unsigned short)(r.z & 0xFFFFu);
            ssw[1][g] = (unsigned short)(r.z >> 16);
            ssw[2][g] = (unsigned short)(r.w & 0xFFFFu);
        }
    }
    __syncthreads();
    // Coalesced writeout: xs plane (20 KB) + 3 sw planes (10 KB each).
    size_t gbase = (size_t)tile * TSLOT;
    {
        const uint4v* s4 = (const uint4v*)sxs;
        uint4v* g4 = (uint4v*)(xs + gbase);
        for (int i = tid; i < TSLOT / 4; i += 512) g4[i] = s4[i];
    }
#pragma unroll
    for (int l = 0; l < 3; ++l) {
        const uint4v* s4 = (const uint4v*)ssw[l];
        uint4v* g4 = (uint4v*)(swp + (size_t)l * NSLOT + gbase);
        for (int i = tid; i < TSLOT / 8; i += 512) g4[i] = s4[i];
    }
    if (tid < NT) {
        int node = tile * NT + tid;
        if (node < N_NODES) {
            int c = lcur[tid];
            count[node] = c < BUCKET ? c : BUCKET;
        }
    }
}

// ---------------------------------------------------------------------------
// 4) Conv layer (R14 body, unchanged): 2 nodes/wave, dwordx4 gathers.
//    rg=lane>>2 (record 0..15), cg=lane&3 (channel quad). One uint4v gather
//    = 16 records x 16 distinct lines per VMEM instruction. Per-layer SoA
//    stream reads. launch_bounds (256,8) per R11 A/B (44.0 vs 45.2).
// ---------------------------------------------------------------------------
template <int LAYER, bool NEXT>
__global__ __launch_bounds__(256, 8) void conv_kernel(const __half* __restrict__ hm,
                            const float* __restrict__ hs,
                            const unsigned int* __restrict__ xs,
                            const unsigned short* __restrict__ swp,
                            const int* __restrict__ count,
                            const __half* __restrict__ table,
                            const float* __restrict__ Wmsg_next,
                            const float* __restrict__ Wself_next,
                            const float* __restrict__ xa_next,
                            __half* __restrict__ hm_out,
                            float* __restrict__ hs_out,
                            float* __restrict__ h_final) {
    __shared__ float sagg[4][2][32];
    int wid = (blockIdx.x * blockDim.x + threadIdx.x) >> 6;
    int na = wid * 2;
    if (na >= N_NODES) return;   // never taken (grid exact) — kept for safety
    int nb = na + 1;
    int lane = threadIdx.x & 63;
    int w  = (threadIdx.x >> 6) & 3;
    int rg = lane >> 2;   // record sub-slot 0..15
    int cg = lane & 3;    // channel quad

    const uint4v* tab4 = (const uint4v*)(table + (size_t)LAYER * TBL_ROWS * D);
    const uint4v* hm4  = (const uint4v*)hm;
    const unsigned short* swb = swp + (size_t)LAYER * NSLOT;

    int cnta = count[na], cntb = count[nb];
    int bega = na * BUCKET, begb = nb * BUCKET;
    int mx = cnta > cntb ? cnta : cntb;

    float acca[8], accb[8];
#pragma unroll
    for (int j = 0; j < 8; ++j) { acca[j] = 0.0f; accb[j] = 0.0f; }

    for (int k = 0; k < BUCKET; k += 32) {
        int r0 = k + rg, r1 = k + 16 + rg;
        bool va0 = r0 < cnta, va1 = r1 < cnta;
        bool vb0 = r0 < cntb, vb1 = r1 < cntb;
        unsigned ua0 = va0 ? xs[bega + r0] : 0u;
        unsigned ua1 = va1 ? xs[bega + r1] : 0u;
        unsigned ub0 = vb0 ? xs[begb + r0] : 0u;
        unsigned ub1 = vb1 ? xs[begb + r1] : 0u;
        float sa0 = va0 ? h2f_bits(swb[bega + r0]) : 0.0f;
        float sa1 = va1 ? h2f_bits(swb[bega + r1]) : 0.0f;
        float sb0 = vb0 ? h2f_bits(swb[begb + r0]) : 0.0f;
        float sb1 = vb1 ? h2f_bits(swb[begb + r1]) : 0.0f;
        uint4v ta0 = tab4[(size_t)(ua0 >> 16) * 4 + cg];
        uint4v ma0 = hm4[(size_t)(ua0 & 0xFFFFu) * 4 + cg];
        uint4v ta1 = tab4[(size_t)(ua1 >> 16) * 4 + cg];
        uint4v ma1 = hm4[(size_t)(ua1 & 0xFFFFu) * 4 + cg];
        uint4v tb0 = tab4[(size_t)(ub0 >> 16) * 4 + cg];
        uint4v mb0 = hm4[(size_t)(ub0 & 0xFFFFu) * 4 + cg];
        uint4v tb1 = tab4[(size_t)(ub1 >> 16) * 4 + cg];
        uint4v mb1 = hm4[(size_t)(ub1 & 0xFFFFu) * 4 + cg];
        asm volatile("" :: "v"(ta0.x), "v"(ma0.x), "v"(ta1.x), "v"(ma1.x),
                           "v"(tb0.x), "v"(mb0.x), "v"(tb1.x), "v"(mb1.x));
        accum8(ta0, ma0, sa0, acca);
        accum8(ta1, ma1, sa1, acca);
        accum8(tb0, mb0, sb0, accb);
        accum8(tb1, mb1, sb1, accb);
        if (k + 32 >= mx) break;
    }

    // Reduce across the 16 record-slots (lanes differing in bits 2..5).
#pragma unroll
    for (int j = 0; j < 8; ++j) {
        acca[j] += __shfl_xor(acca[j], 4);
        acca[j] += __shfl_xor(acca[j], 8);
        acca[j] += __shfl_xor(acca[j], 16);
        acca[j] += __shfl_xor(acca[j], 32);
        accb[j] += __shfl_xor(accb[j], 4);
        accb[j] += __shfl_xor(accb[j], 8);
        accb[j] += __shfl_xor(accb[j], 16);
        accb[j] += __shfl_xor(accb[j], 32);
    }
    if (rg == 0) {  // lanes 0..3 hold all channel quads (replicated sums)
#pragma unroll
        for (int j = 0; j < 8; ++j) {
            sagg[w][0][cg * 8 + j] = acca[j];
            sagg[w][1][cg * 8 + j] = accb[j];
        }
    }
    __syncthreads();

    int c = lane & 31;
    int hi = lane >> 5;
    int mynode = hi ? nb : na;
    float agg = sagg[w][hi][c];

    float hn = silu(agg + hs[mynode * D + c]);
    if (NEXT) {
        float m = 0.0f, s2 = 0.0f;
#pragma unroll
        for (int j = 0; j < D; ++j) {
            float hj = __shfl(hn, j, 32);  // width-32: each half reads its own node
            m  = fmaf(hj, Wmsg_next[j * D + c], m);
            s2 = fmaf(hj, Wself_next[j * D + c], s2);
        }
        hm_out[mynode * D + c] = __float2half(m);
        hs_out[mynode * D + c] = s2 + xa_next[mynode * D + c];
    } else {
        h_final[mynode * D + c] = hn;
    }
}

// ---------------------------------------------------------------------------
// 5) Readout: per-node MLP scalar, wave-aggregated segment-sum (batch sorted
//    -> ~782 wave-level atomics onto 64 floats — measured ~12 us).
// ---------------------------------------------------------------------------
__global__ void readout_kernel(const float* __restrict__ h,
                               const int* __restrict__ batch,
                               const float* __restrict__ Wp1,
                               const float* __restrict__ bp1,
                               const float* __restrict__ Wp2,
                               const float* __restrict__ bp2,
                               float* __restrict__ out) {
    int n = blockIdx.x * blockDim.x + threadIdx.x;
    float s = 0.0f;
    int b = -1;
    if (n < N_NODES) {
        b = batch[n];
        const float* hrow = h + n * D;
        float acc2 = bp2[0];
#pragma unroll
        for (int m = 0; m < 16; ++m) {
            float a = bp1[m];
#pragma unroll
            for (int j = 0; j < D; ++j) a += hrow[j] * Wp1[j * 16 + m];
            acc2 += silu(a) * Wp2[m];
        }
        s = acc2;  // SCALE=1, SHIFT=0 baked in
    }
    unsigned long long valid = __ballot(n < N_NODES);
    if (valid == 0ull) return;
    int firstLane = __ffsll(valid) - 1;
    int b0v = __shfl(b, firstLane);
    bool ok = (b == b0v) || (n >= N_NODES);
    if (__all(ok)) {
#pragma unroll
        for (int o = 32; o > 0; o >>= 1) s += __shfl_down(s, o);
        if ((threadIdx.x & 63) == 0) atomicAdd(out + b0v, s);
    } else {
        if (n < N_NODES) atomicAdd(out + b, s);
    }
}

// ---------------------------------------------------------------------------
extern "C" void kernel_launch(void* const* d_in, const int* in_sizes, int n_in,
                              void* d_out, int out_size, void* d_ws, size_t ws_size,
                              hipStream_t stream) {
    const int*   x      = (const int*)d_in[0];
    const float* pos    = (const float*)d_in[1];
    const int*   eidx   = (const int*)d_in[2];
    const float* period = (const float*)d_in[3];
    const int*   batch  = (const int*)d_in[4];
    const float* W_elem = (const float*)d_in[5];
    const float* W0     = (const float*)d_in[6];
    const float* b0     = (const float*)d_in[7];
    const float* Wr1    = (const float*)d_in[8];
    const float* br1    = (const float*)d_in[9];
    const float* Wr2    = (const float*)d_in[10];
    const float* Wmsg   = (const float*)d_in[11];
    const float* Wattr  = (const float*)d_in[12];
    const float* Wself  = (const float*)d_in[13];
    const float* bconv  = (const float*)d_in[14];
    const float* wsh    = (const float*)d_in[15];
    const float* Wp1    = (const float*)d_in[16];
    const float* bp1    = (const float*)d_in[17];
    const float* Wp2    = (const float*)d_in[18];
    const float* bp2    = (const float*)d_in[19];

    char* base = (char*)d_ws;
    size_t off = 0;
    auto carve = [&](size_t bytes) -> void* {
        void* p = base + off;
        off = (off + bytes + 255) & ~(size_t)255;
        return p;
    };
    __half*         hm_a        = (__half*)carve((size_t)N_NODES * D * 2);
    __half*         hm_b        = (__half*)carve((size_t)N_NODES * D * 2);
    float*          hs_a        = (float*)carve((size_t)N_NODES * D * 4);
    float*          hs_b        = (float*)carve((size_t)N_NODES * D * 4);
    float*          xa1         = (float*)carve((size_t)N_NODES * D * 4);
    float*          xa2         = (float*)carve((size_t)N_NODES * D * 4);
    float*          h_final     = (float*)carve((size_t)N_NODES * D * 4);
    unsigned int*   xs          = (unsigned int*)carve((size_t)NSLOT * 4);
    unsigned short* swp         = (unsigned short*)carve((size_t)3 * NSLOT * 2);
    uint4v*         bins        = (uint4v*)carve((size_t)NTILES * TCAP * 16);
    int*            tile_cursor = (int*)carve((size_t)NTILES * 4);
    int*            count       = (int*)carve((size_t)NTILES * NT * 4);
    __half*         table       = (__half*)carve((size_t)3 * TBL_ROWS * D * 2);
    (void)ws_size; (void)in_sizes; (void)n_in; (void)out_size;

    hipMemsetAsync(tile_cursor, 0, (size_t)NTILES * 4, stream);
    mega_kernel<<<MEGA_BLKS, MTHREADS, 0, stream>>>(
        eidx, pos, period, wsh, tile_cursor, bins,
        x, W_elem, W0, b0, Wmsg + 0 * D * D, Wself + 0 * D * D, Wattr, bconv,
        hm_a, hs_a, xa1, xa2, (float*)d_out,
        Wr1, br1, Wr2, table);
    shuffle_kernel<<<NTILES, 512, 0, stream>>>(bins, tile_cursor, xs, swp, count);

    // 2 nodes per wave: 25000 waves -> 6250 blocks of 256 (exact).
    int cwaves = (N_NODES + 1) / 2;
    int cgrid  = (cwaves * 64 + 255) / 256;
    conv_kernel<0, true><<<cgrid, 256, 0, stream>>>(
        hm_a, hs_a, xs, swp, count, table, Wmsg + 1 * D * D, Wself + 1 * D * D, xa1,
        hm_b, hs_b, nullptr);
    conv_kernel<1, true><<<cgrid, 256, 0, stream>>>(
        hm_b, hs_b, xs, swp, count, table, Wmsg + 2 * D * D, Wself + 2 * D * D, xa2,
        hm_a, hs_a, nullptr);
    conv_kernel<2, false><<<cgrid, 256, 0, stream>>>(
        hm_a, hs_a, xs, swp, count, table, nullptr, nullptr, nullptr,
        nullptr, nullptr, h_final);

    readout_kernel<<<(N_NODES + 255) / 256, 256, 0, stream>>>(h_final, batch, Wp1, bp1, Wp2, bp2,
                                                              (float*)d_out);
}

// Round 20
// 342.782 us; speedup vs baseline: 1.0499x; 1.0499x over previous
//
#include <hip/hip_runtime.h>
#include <hip/hip_fp16.h>
#include <math.h>

// Problem constants (from reference file)
constexpr int N_NODES  = 50000;
constexpr int N_EDGES  = 1600000;
constexpr int G_GRAPHS = 64;
constexpr int D        = 32;
constexpr int D_ATTR   = 16;
constexpr int N_RBF    = 8;

// rw(len) lookup table: 8192 intervals over [0, LMAX], nearest-neighbor, fp16.
constexpr int   TBL      = 8192;
constexpr int   TBL_ROWS = TBL + 1;
constexpr float LMAX     = 10.0f;

// Final per-node bucket layout (SoA for coalesced conv reads). deg ~ Poisson(32).
constexpr int BUCKET = 80;

// dst-tiles of 64 nodes; per-tile contiguous streams filled by counting sort.
constexpr int NT     = 64;
constexpr int NTILES = (N_NODES + NT - 1) / NT;  // 782
constexpr int TCAP   = 2432;                     // Poisson(2048) +8.5 sigma
// FINAL (R18 configuration, session best 347.5us; session 404 -> 347.5):
// prep(init+table) -> scatter(combined: per-block LDS hist + one tile_cursor
// atomic per nonzero tile per block + LDS-ranked scatter) -> LDS-staged
// shuffle -> conv x3 -> readout. 7 dispatches.
// DO-NOT-REPEAT ledger (all measured this session):
//  r16: PER-EDGE returning atomics, 782 counters (~2046/addr) -> 380us.
//    (Per-BLOCK cursor atomics, <=391/addr chains, are fine — R4/R18.)
//  R12: direct scattered SoA writes (4 planes/record) -> 240MB WRITE, 130us.
//  R13: 16B AoS bucket for conv -> conv streams 16B/rec x3 layers, +30us.
//  R15 WIN: LDS-staged shuffle (coalesced 4-plane writeout) -13.4us.
//  R16 WIN: merged prep -5.3us. R17: (512,8) on prep regressed (VGPR squeeze;
//    prep is occupancy-insensitive).
//  R18 WIN: scan deleted, hist folded into scatter (R4 form) -8us.
//  R19: mega(scatter+init+table) fusion -> NO overlap (114us ~= 57+57);
//    block-range fusion only overlaps if range0 << resident capacity.
//  r22/R9: conv accumulation via LDS atomicAdd -> 356us/conv (7x).
//  r23/R10: conv software-pipelining folded by compiler — neutral.
//  R11: conv (256,8) adopted (44.0 vs 45.2).
constexpr int EPB      = 4096;                         // R4/R18 scatter config
constexpr int STHREADS = 1024;
constexpr int EPV      = EPB / STHREADS;               // 4 edges/thread
constexpr int NBLK1    = (N_EDGES + EPB - 1) / EPB;    // 391

constexpr int NSLOT = NTILES * NT * BUCKET;  // bucket slots total
constexpr int TSLOT = NT * BUCKET;           // 5120 slots per tile

// prep kernel block ranges (512 threads/block)
constexpr int INIT_BLKS  = (N_NODES * 32 + 511) / 512;          // 3125
constexpr int TABLE_BLKS = (3 * TBL_ROWS + 511) / 512;          // 49
constexpr int PREP_BLKS  = INIT_BLKS + TABLE_BLKS;              // 3174

typedef unsigned int  uint4v  __attribute__((ext_vector_type(4)));
typedef unsigned int  uint2v  __attribute__((ext_vector_type(2)));

__device__ __forceinline__ float silu(float x) {
    return x / (1.0f + __expf(-x));
}
__device__ __forceinline__ float h2f_bits(unsigned short u) {
    return __half2float(__ushort_as_half(u));
}
__device__ __forceinline__ __half2 h2u(unsigned v) {
    union { unsigned u; __half2 h; } c; c.u = v; return c.h;
}

// acc[j] += (tab*hm)[channel cg*8+j] * sw for one record's 8-channel quad.
__device__ __forceinline__ void accum8(uint4v t, uint4v m, float sw, float (&acc)[8]) {
    float2 p0 = __half22float2(__hmul2(h2u(t.x), h2u(m.x)));
    float2 p1 = __half22float2(__hmul2(h2u(t.y), h2u(m.y)));
    float2 p2 = __half22float2(__hmul2(h2u(t.z), h2u(m.z)));
    float2 p3 = __half22float2(__hmul2(h2u(t.w), h2u(m.w)));
    acc[0] = fmaf(p0.x, sw, acc[0]); acc[1] = fmaf(p0.y, sw, acc[1]);
    acc[2] = fmaf(p1.x, sw, acc[2]); acc[3] = fmaf(p1.y, sw, acc[3]);
    acc[4] = fmaf(p2.x, sw, acc[4]); acc[5] = fmaf(p2.y, sw, acc[5]);
    acc[6] = fmaf(p3.x, sw, acc[6]); acc[7] = fmaf(p3.y, sw, acc[7]);
}

// ---------------------------------------------------------------------------
// 1) Prep (init+table). Default launch bounds (R17: waves-arg regressed this
//    occupancy-insensitive kernel). Init branch zeroes tile_cursor and out.
// ---------------------------------------------------------------------------
__global__ __launch_bounds__(512) void prep_kernel(const int* __restrict__ x,
                                                   const float* __restrict__ W_elem,
                                                   const float* __restrict__ W0,
                                                   const float* __restrict__ b0,
                                                   const float* __restrict__ Wmsg0,
                                                   const float* __restrict__ Wself0,
                                                   const float* __restrict__ Wattr,
                                                   const float* __restrict__ bconv,
                                                   __half* __restrict__ hm0,
                                                   float* __restrict__ hs0,
                                                   float* __restrict__ xa1,
                                                   float* __restrict__ xa2,
                                                   int* __restrict__ tile_cursor,
                                                   float* __restrict__ out,
                                                   const float* __restrict__ Wr1,
                                                   const float* __restrict__ br1,
                                                   const float* __restrict__ Wr2,
                                                   __half* __restrict__ table) {
    int tid = threadIdx.x;
    int blk = blockIdx.x;

    if (blk < INIT_BLKS) {
        // ---- node-init branch ----
        int t = blk * 512 + tid;
        if (t < G_GRAPHS) out[t] = 0.0f;
        if (t < NTILES) tile_cursor[t] = 0;
        int n = t >> 5, c = t & 31;
        if (n >= N_NODES) return;
        int sp = x[n];
        const float* we = W_elem + sp * D_ATTR;
        float xv = (c < D_ATTR) ? we[c] : 0.0f;
        float acc = b0[c];
#pragma unroll
        for (int a = 0; a < D_ATTR; ++a) acc += we[a] * W0[a * D + c];
        float m = 0.0f, s = 0.0f;
#pragma unroll
        for (int j = 0; j < D; ++j) {
            float hj = __shfl(acc, j, 32);
            m = fmaf(hj, Wmsg0[j * D + c], m);
            s = fmaf(hj, Wself0[j * D + c], s);
        }
        float a0 = bconv[0 * D + c], a1 = bconv[1 * D + c], a2 = bconv[2 * D + c];
#pragma unroll
        for (int j = 0; j < D_ATTR; ++j) {
            float xj = __shfl(xv, j, 32);
            a0 = fmaf(xj, Wattr[0 * D_ATTR * D + j * D + c], a0);
            a1 = fmaf(xj, Wattr[1 * D_ATTR * D + j * D + c], a1);
            a2 = fmaf(xj, Wattr[2 * D_ATTR * D + j * D + c], a2);
        }
        hm0[n * D + c] = __float2half(m);
        hs0[n * D + c] = s + a0;
        xa1[n * D + c] = a1;
        xa2[n * D + c] = a2;
        return;
    }
    // ---- table branch ----
    {
        int t = (blk - INIT_BLKS) * 512 + tid;
        if (t >= 3 * TBL_ROWS) return;
        int l = t / TBL_ROWS;
        int idx = t % TBL_ROWS;
        float len = (float)idx * (LMAX / (float)TBL);
        const float gamma = (8.0f / 5.0f) * (8.0f / 5.0f);  // (N_RBF/CUTOFF)^2
        float rbf[N_RBF];
#pragma unroll
        for (int k = 0; k < N_RBF; ++k) {
            float dd = len - (float)k * (5.0f / 7.0f);  // linspace(0, CUTOFF, 8)
            rbf[k] = __expf(-gamma * dd * dd);
        }
        float outv[D];
#pragma unroll
        for (int c = 0; c < D; ++c) outv[c] = 0.0f;
        for (int j = 0; j < D; ++j) {
            float z = br1[l * D + j];
#pragma unroll
            for (int k = 0; k < N_RBF; ++k) z += rbf[k] * Wr1[l * N_RBF * D + k * D + j];
            z = fmaxf(z, 0.0f);
            const float* w2 = Wr2 + l * D * D + j * D;
#pragma unroll
            for (int c = 0; c < D; ++c) outv[c] += z * w2[c];
        }
        __half* dst = table + ((size_t)(l * TBL_ROWS + idx)) * D;
#pragma unroll
        for (int c = 0; c < D; ++c) dst[c] = __float2half(outv[c]);
    }
}

// ---------------------------------------------------------------------------
// 2) Scatter (R4/R18-combined, measured 57us): per-block LDS histogram ->
//    ONE tile_cursor returning-atomic per nonzero tile per block (chain
//    depth <= 391 per tile addr — safe regime) -> LDS-ranked scatter into
//    per-tile contiguous bins. 1024-thread blocks, EPB=4096, 391 blocks.
//    bin rec = { src | (tbl_idx<<16), dstLocal, sw0|sw1<<16, sw2 }
// ---------------------------------------------------------------------------
__global__ __launch_bounds__(STHREADS, 4) void scatter_kernel(const int* __restrict__ eidx,
                                                              const float* __restrict__ pos,
                                                              const float* __restrict__ period,
                                                              const float* __restrict__ wsh,
                                                              int* __restrict__ tile_cursor,
                                                              uint4v* __restrict__ bins) {
    __shared__ int hist[NTILES];
    __shared__ int basev[NTILES];
    int tid = threadIdx.x;
    int e0 = blockIdx.x * EPB;
    for (int i = tid; i < NTILES; i += STHREADS) hist[i] = 0;
    __syncthreads();
#pragma unroll
    for (int i = 0; i < EPV; ++i) {
        int e = e0 + tid + STHREADS * i;
        if (e < N_EDGES) atomicAdd(&hist[eidx[N_EDGES + e] >> 6], 1);
    }
    __syncthreads();
    for (int t = tid; t < NTILES; t += STHREADS) {
        int cnt = hist[t];
        basev[t] = (cnt > 0) ? atomicAdd(&tile_cursor[t], cnt) : 0;
        hist[t] = 0;
    }
    __syncthreads();

    // Batched gather phase: 4 independent latency chains per thread.
    int   sarr[EPV], darr[EPV];
    float vx[EPV], vy[EPV], vz[EPV];
#pragma unroll
    for (int i = 0; i < EPV; ++i) {
        int e  = e0 + tid + STHREADS * i;
        int ec = (e < N_EDGES) ? e : (N_EDGES - 1);
        int s = eidx[ec];
        int d = eidx[N_EDGES + ec];
        sarr[i] = s;
        darr[i] = d;
        vx[i] = pos[d * 3 + 0] - pos[s * 3 + 0] + period[ec * 3 + 0];
        vy[i] = pos[d * 3 + 1] - pos[s * 3 + 1] + period[ec * 3 + 1];
        vz[i] = pos[d * 3 + 2] - pos[s * 3 + 2] + period[ec * 3 + 2];
    }
    asm volatile("" ::
        "v"(vx[0]), "v"(vx[1]), "v"(vx[2]), "v"(vx[3]),
        "v"(vy[0]), "v"(vy[1]), "v"(vy[2]), "v"(vy[3]),
        "v"(vz[0]), "v"(vz[1]), "v"(vz[2]), "v"(vz[3]),
        "v"(sarr[0]), "v"(sarr[1]), "v"(sarr[2]), "v"(sarr[3]),
        "v"(darr[0]), "v"(darr[1]), "v"(darr[2]), "v"(darr[3]));
#pragma unroll
    for (int i = 0; i < EPV; ++i) {
        int e = e0 + tid + STHREADS * i;
        if (e >= N_EDGES) continue;
        float len = sqrtf(vx[i] * vx[i] + vy[i] * vy[i] + vz[i] * vz[i]);
        float inv = 1.0f / (len + 1e-9f);
        int idx = (int)fminf(len * ((float)TBL / LMAX) + 0.5f, (float)TBL);
        float sw[3];
#pragma unroll
        for (int l = 0; l < 3; ++l)
            sw[l] = wsh[l * 4 + 0] +
                    (vx[i] * wsh[l * 4 + 1] + vy[i] * wsh[l * 4 + 2] + vz[i] * wsh[l * 4 + 3]) * inv;
        int tile = darr[i] >> 6;
        int rank = atomicAdd(&hist[tile], 1);
        int slot = basev[tile] + rank;
        if (slot < TCAP) {
            unsigned u0 = (unsigned)__half_as_ushort(__float2half(sw[0]));
            unsigned u1 = (unsigned)__half_as_ushort(__float2half(sw[1]));
            unsigned u2 = (unsigned)__half_as_ushort(__float2half(sw[2]));
            uint4v r;
            r.x = (unsigned)sarr[i] | ((unsigned)idx << 16);
            r.y = (unsigned)(darr[i] & (NT - 1));
            r.z = u0 | (u1 << 16);
            r.w = u2;
            bins[(size_t)tile * TCAP + slot] = r;
        }
    }
}

// ---------------------------------------------------------------------------
// 2b) Shuffle (R15 WIN form): block-per-tile, LDS-staged re-rank then
//     COALESCED writeout of all 4 planes. Zero scattered global writes.
//     tile_total = tile_cursor after scatter (clamped by TCAP).
// ---------------------------------------------------------------------------
__global__ __launch_bounds__(512) void shuffle_kernel(const uint4v* __restrict__ bins,
                                                      const int* __restrict__ tile_total,
                                                      unsigned int* __restrict__ xs,
                                                      unsigned short* __restrict__ swp,
                                                      int* __restrict__ count) {
    __shared__ int lcur[NT];
    __shared__ unsigned sxs[TSLOT];                 // 20 KB
    __shared__ unsigned short ssw[3][TSLOT];        // 30 KB
    int tile = blockIdx.x;
    int tid = threadIdx.x;
    if (tid < NT) lcur[tid] = 0;
    __syncthreads();
    int cnt = tile_total[tile];
    if (cnt > TCAP) cnt = TCAP;
    const uint4v* base = bins + (size_t)tile * TCAP;
    for (int i = tid; i < cnt; i += 512) {
        uint4v r = __builtin_nontemporal_load(base + i);
        int dl = (int)(r.y & 63u);
        int slot = atomicAdd(&lcur[dl], 1);
        if (slot < BUCKET) {
            int g = dl * BUCKET + slot;
            sxs[g] = r.x;
            ssw[0][g] = (unsigned short)(r.z & 0xFFFFu);
            ssw[1][g] = (unsigned short)(r.z >> 16);
            ssw[2][g] = (unsigned short)(r.w & 0xFFFFu);
        }
    }
    __syncthreads();
    // Coalesced writeout: xs plane (20 KB) + 3 sw planes (10 KB each).
    size_t gbase = (size_t)tile * TSLOT;
    {
        const uint4v* s4 = (const uint4v*)sxs;
        uint4v* g4 = (uint4v*)(xs + gbase);
        for (int i = tid; i < TSLOT / 4; i += 512) g4[i] = s4[i];
    }
#pragma unroll
    for (int l = 0; l < 3; ++l) {
        const uint4v* s4 = (const uint4v*)ssw[l];
        uint4v* g4 = (uint4v*)(swp + (size_t)l * NSLOT + gbase);
        for (int i = tid; i < TSLOT / 8; i += 512) g4[i] = s4[i];
    }
    if (tid < NT) {
        int node = tile * NT + tid;
        if (node < N_NODES) {
            int c = lcur[tid];
            count[node] = c < BUCKET ? c : BUCKET;
        }
    }
}

// ---------------------------------------------------------------------------
// 4) Conv layer (R14 body): 2 nodes/wave, dwordx4 gathers. rg=lane>>2
//    (record 0..15), cg=lane&3 (channel quad). One uint4v gather = 16
//    records x 16 distinct lines per VMEM instruction. Per-layer SoA
//    stream reads. launch_bounds (256,8) per R11 A/B (44.0 vs 45.2).
// ---------------------------------------------------------------------------
template <int LAYER, bool NEXT>
__global__ __launch_bounds__(256, 8) void conv_kernel(const __half* __restrict__ hm,
                            const float* __restrict__ hs,
                            const unsigned int* __restrict__ xs,
                            const unsigned short* __restrict__ swp,
                            const int* __restrict__ count,
                            const __half* __restrict__ table,
                            const float* __restrict__ Wmsg_next,
                            const float* __restrict__ Wself_next,
                            const float* __restrict__ xa_next,
                            __half* __restrict__ hm_out,
                            float* __restrict__ hs_out,
                            float* __restrict__ h_final) {
    __shared__ float sagg[4][2][32];
    int wid = (blockIdx.x * blockDim.x + threadIdx.x) >> 6;
    int na = wid * 2;
    if (na >= N_NODES) return;   // never taken (grid exact) — kept for safety
    int nb = na + 1;
    int lane = threadIdx.x & 63;
    int w  = (threadIdx.x >> 6) & 3;
    int rg = lane >> 2;   // record sub-slot 0..15
    int cg = lane & 3;    // channel quad

    const uint4v* tab4 = (const uint4v*)(table + (size_t)LAYER * TBL_ROWS * D);
    const uint4v* hm4  = (const uint4v*)hm;
    const unsigned short* swb = swp + (size_t)LAYER * NSLOT;

    int cnta = count[na], cntb = count[nb];
    int bega = na * BUCKET, begb = nb * BUCKET;
    int mx = cnta > cntb ? cnta : cntb;

    float acca[8], accb[8];
#pragma unroll
    for (int j = 0; j < 8; ++j) { acca[j] = 0.0f; accb[j] = 0.0f; }

    for (int k = 0; k < BUCKET; k += 32) {
        int r0 = k + rg, r1 = k + 16 + rg;
        bool va0 = r0 < cnta, va1 = r1 < cnta;
        bool vb0 = r0 < cntb, vb1 = r1 < cntb;
        unsigned ua0 = va0 ? xs[bega + r0] : 0u;
        unsigned ua1 = va1 ? xs[bega + r1] : 0u;
        unsigned ub0 = vb0 ? xs[begb + r0] : 0u;
        unsigned ub1 = vb1 ? xs[begb + r1] : 0u;
        float sa0 = va0 ? h2f_bits(swb[bega + r0]) : 0.0f;
        float sa1 = va1 ? h2f_bits(swb[bega + r1]) : 0.0f;
        float sb0 = vb0 ? h2f_bits(swb[begb + r0]) : 0.0f;
        float sb1 = vb1 ? h2f_bits(swb[begb + r1]) : 0.0f;
        uint4v ta0 = tab4[(size_t)(ua0 >> 16) * 4 + cg];
        uint4v ma0 = hm4[(size_t)(ua0 & 0xFFFFu) * 4 + cg];
        uint4v ta1 = tab4[(size_t)(ua1 >> 16) * 4 + cg];
        uint4v ma1 = hm4[(size_t)(ua1 & 0xFFFFu) * 4 + cg];
        uint4v tb0 = tab4[(size_t)(ub0 >> 16) * 4 + cg];
        uint4v mb0 = hm4[(size_t)(ub0 & 0xFFFFu) * 4 + cg];
        uint4v tb1 = tab4[(size_t)(ub1 >> 16) * 4 + cg];
        uint4v mb1 = hm4[(size_t)(ub1 & 0xFFFFu) * 4 + cg];
        asm volatile("" :: "v"(ta0.x), "v"(ma0.x), "v"(ta1.x), "v"(ma1.x),
                           "v"(tb0.x), "v"(mb0.x), "v"(tb1.x), "v"(mb1.x));
        accum8(ta0, ma0, sa0, acca);
        accum8(ta1, ma1, sa1, acca);
        accum8(tb0, mb0, sb0, accb);
        accum8(tb1, mb1, sb1, accb);
        if (k + 32 >= mx) break;
    }

    // Reduce across the 16 record-slots (lanes differing in bits 2..5).
#pragma unroll
    for (int j = 0; j < 8; ++j) {
        acca[j] += __shfl_xor(acca[j], 4);
        acca[j] += __shfl_xor(acca[j], 8);
        acca[j] += __shfl_xor(acca[j], 16);
        acca[j] += __shfl_xor(acca[j], 32);
        accb[j] += __shfl_xor(accb[j], 4);
        accb[j] += __shfl_xor(accb[j], 8);
        accb[j] += __shfl_xor(accb[j], 16);
        accb[j] += __shfl_xor(accb[j], 32);
    }
    if (rg == 0) {  // lanes 0..3 hold all channel quads (replicated sums)
#pragma unroll
        for (int j = 0; j < 8; ++j) {
            sagg[w][0][cg * 8 + j] = acca[j];
            sagg[w][1][cg * 8 + j] = accb[j];
        }
    }
    __syncthreads();

    int c = lane & 31;
    int hi = lane >> 5;
    int mynode = hi ? nb : na;
    float agg = sagg[w][hi][c];

    float hn = silu(agg + hs[mynode * D + c]);
    if (NEXT) {
        float m = 0.0f, s2 = 0.0f;
#pragma unroll
        for (int j = 0; j < D; ++j) {
            float hj = __shfl(hn, j, 32);  // width-32: each half reads its own node
            m  = fmaf(hj, Wmsg_next[j * D + c], m);
            s2 = fmaf(hj, Wself_next[j * D + c], s2);
        }
        hm_out[mynode * D + c] = __float2half(m);
        hs_out[mynode * D + c] = s2 + xa_next[mynode * D + c];
    } else {
        h_final[mynode * D + c] = hn;
    }
}

// ---------------------------------------------------------------------------
// 5) Readout: per-node MLP scalar, wave-aggregated segment-sum (batch sorted
//    -> ~782 wave-level atomics onto 64 floats — measured ~12 us).
// ---------------------------------------------------------------------------
__global__ void readout_kernel(const float* __restrict__ h,
                               const int* __restrict__ batch,
                               const float* __restrict__ Wp1,
                               const float* __restrict__ bp1,
                               const float* __restrict__ Wp2,
                               const float* __restrict__ bp2,
                               float* __restrict__ out) {
    int n = blockIdx.x * blockDim.x + threadIdx.x;
    float s = 0.0f;
    int b = -1;
    if (n < N_NODES) {
        b = batch[n];
        const float* hrow = h + n * D;
        float acc2 = bp2[0];
#pragma unroll
        for (int m = 0; m < 16; ++m) {
            float a = bp1[m];
#pragma unroll
            for (int j = 0; j < D; ++j) a += hrow[j] * Wp1[j * 16 + m];
            acc2 += silu(a) * Wp2[m];
        }
        s = acc2;  // SCALE=1, SHIFT=0 baked in
    }
    unsigned long long valid = __ballot(n < N_NODES);
    if (valid == 0ull) return;
    int firstLane = __ffsll(valid) - 1;
    int b0v = __shfl(b, firstLane);
    bool ok = (b == b0v) || (n >= N_NODES);
    if (__all(ok)) {
#pragma unroll
        for (int o = 32; o > 0; o >>= 1) s += __shfl_down(s, o);
        if ((threadIdx.x & 63) == 0) atomicAdd(out + b0v, s);
    } else {
        if (n < N_NODES) atomicAdd(out + b, s);
    }
}

// ---------------------------------------------------------------------------
extern "C" void kernel_launch(void* const* d_in, const int* in_sizes, int n_in,
                              void* d_out, int out_size, void* d_ws, size_t ws_size,
                              hipStream_t stream) {
    const int*   x      = (const int*)d_in[0];
    const float* pos    = (const float*)d_in[1];
    const int*   eidx   = (const int*)d_in[2];
    const float* period = (const float*)d_in[3];
    const int*   batch  = (const int*)d_in[4];
    const float* W_elem = (const float*)d_in[5];
    const float* W0     = (const float*)d_in[6];
    const float* b0     = (const float*)d_in[7];
    const float* Wr1    = (const float*)d_in[8];
    const float* br1    = (const float*)d_in[9];
    const float* Wr2    = (const float*)d_in[10];
    const float* Wmsg   = (const float*)d_in[11];
    const float* Wattr  = (const float*)d_in[12];
    const float* Wself  = (const float*)d_in[13];
    const float* bconv  = (const float*)d_in[14];
    const float* wsh    = (const float*)d_in[15];
    const float* Wp1    = (const float*)d_in[16];
    const float* bp1    = (const float*)d_in[17];
    const float* Wp2    = (const float*)d_in[18];
    const float* bp2    = (const float*)d_in[19];

    char* base = (char*)d_ws;
    size_t off = 0;
    auto carve = [&](size_t bytes) -> void* {
        void* p = base + off;
        off = (off + bytes + 255) & ~(size_t)255;
        return p;
    };
    __half*         hm_a        = (__half*)carve((size_t)N_NODES * D * 2);
    __half*         hm_b        = (__half*)carve((size_t)N_NODES * D * 2);
    float*          hs_a        = (float*)carve((size_t)N_NODES * D * 4);
    float*          hs_b        = (float*)carve((size_t)N_NODES * D * 4);
    float*          xa1         = (float*)carve((size_t)N_NODES * D * 4);
    float*          xa2         = (float*)carve((size_t)N_NODES * D * 4);
    float*          h_final     = (float*)carve((size_t)N_NODES * D * 4);
    unsigned int*   xs          = (unsigned int*)carve((size_t)NSLOT * 4);
    unsigned short* swp         = (unsigned short*)carve((size_t)3 * NSLOT * 2);
    uint4v*         bins        = (uint4v*)carve((size_t)NTILES * TCAP * 16);
    int*            tile_cursor = (int*)carve((size_t)NTILES * 4);
    int*            count       = (int*)carve((size_t)NTILES * NT * 4);
    __half*         table       = (__half*)carve((size_t)3 * TBL_ROWS * D * 2);
    (void)ws_size; (void)in_sizes; (void)n_in; (void)out_size;

    prep_kernel<<<PREP_BLKS, 512, 0, stream>>>(
        x, W_elem, W0, b0, Wmsg + 0 * D * D, Wself + 0 * D * D, Wattr, bconv,
        hm_a, hs_a, xa1, xa2, tile_cursor, (float*)d_out,
        Wr1, br1, Wr2, table);
    scatter_kernel<<<NBLK1, STHREADS, 0, stream>>>(eidx, pos, period, wsh,
                                                   tile_cursor, bins);
    shuffle_kernel<<<NTILES, 512, 0, stream>>>(bins, tile_cursor, xs, swp, count);

    // 2 nodes per wave: 25000 waves -> 6250 blocks of 256 (exact).
    int cwaves = (N_NODES + 1) / 2;
    int cgrid  = (cwaves * 64 + 255) / 256;
    conv_kernel<0, true><<<cgrid, 256, 0, stream>>>(
        hm_a, hs_a, xs, swp, count, table, Wmsg + 1 * D * D, Wself + 1 * D * D, xa1,
        hm_b, hs_b, nullptr);
    conv_kernel<1, true><<<cgrid, 256, 0, stream>>>(
        hm_b, hs_b, xs, swp, count, table, Wmsg + 2 * D * D, Wself + 2 * D * D, xa2,
        hm_a, hs_a, nullptr);
    conv_kernel<2, false><<<cgrid, 256, 0, stream>>>(
        hm_a, hs_a, xs, swp, count, table, nullptr, nullptr, nullptr,
        nullptr, nullptr, h_final);

    readout_kernel<<<(N_NODES + 255) / 256, 256, 0, stream>>>(h_final, batch, Wp1, bp1, Wp2, bp2,
                                                              (float*)d_out);
}